// Round 4
// baseline (66.997 us; speedup 1.0000x reference)
//
#include <hip/hip_runtime.h>
#include <hip/hip_bf16.h>

#define HW 512
#define CH 3

typedef float v4f __attribute__((ext_vector_type(4)));

// Each thread: 4 output rows x 8 pixels x 3 output channels (96 outputs).
// Weights wave-uniform (expert index readfirstlane'd) -> scalar regs.
// Input rows streamed one at a time (10-float buffer) to cap VGPR.
__global__ __launch_bounds__(256) void moe_conv3x3_kernel(
    const float* __restrict__ img,   // [B,3,512,512]
    const float* __restrict__ Wt,    // [E,3,3,3,3] OIHW per expert
    const float* __restrict__ bias,  // [E,3]
    const int*   __restrict__ alloc, // [B]
    float*       __restrict__ out)   // [B,3,512,512]
{
    const int b = blockIdx.y;
    int e = alloc[b];
    e = __builtin_amdgcn_readfirstlane(e);   // wave-uniform -> s_loads

    const float* we = Wt + (size_t)e * (CH * CH * 9);

    float bv[CH];
#pragma unroll
    for (int oc = 0; oc < CH; ++oc) bv[oc] = bias[(size_t)e * CH + oc];

    // 64 col-blocks (x8 px) x 128 row-blocks (x4 rows) per sample
    const int idx = blockIdx.x * 256 + threadIdx.x;  // 0..8191
    const int w8  = (idx & 63) * 8;                  // 0..504 step 8
    const int hb  = (idx >> 6) * 4;                  // 0..508 step 4

    const float* inb = img + (size_t)b * CH * HW * HW;

    float acc[CH][4][8];
#pragma unroll
    for (int oc = 0; oc < CH; ++oc)
#pragma unroll
        for (int r = 0; r < 4; ++r)
#pragma unroll
            for (int j = 0; j < 8; ++j) acc[oc][r][j] = bv[oc];

#pragma unroll
    for (int ci = 0; ci < CH; ++ci) {
        const float* inc = inb + (size_t)ci * HW * HW;

        // 27 uniform weights for this input channel (scalar regs)
        float wk[CH][3][3];
#pragma unroll
        for (int oc = 0; oc < CH; ++oc)
#pragma unroll
            for (int kh = 0; kh < 3; ++kh)
#pragma unroll
                for (int kw = 0; kw < 3; ++kw)
                    wk[oc][kh][kw] = we[((oc * CH + ci) * 3 + kh) * 3 + kw];

#pragma unroll
        for (int ri = 0; ri < 6; ++ri) {            // input rows hb-1 .. hb+4
            const int hr = hb + ri - 1;
            float row[10];
            if (hr >= 0 && hr < HW) {               // wave-uniform branch
                const float* rsrc = inc + (size_t)hr * HW + w8;
                const v4f a = *(const v4f*)rsrc;
                const v4f c = *(const v4f*)(rsrc + 4);
                row[1] = a.x; row[2] = a.y; row[3] = a.z; row[4] = a.w;
                row[5] = c.x; row[6] = c.y; row[7] = c.z; row[8] = c.w;
                row[0] = (w8 > 0)      ? rsrc[-1] : 0.0f;
                row[9] = (w8 < HW - 8) ? rsrc[8]  : 0.0f;
            } else {
#pragma unroll
                for (int j = 0; j < 10; ++j) row[j] = 0.0f;
            }

            // input row ri -> output rows r with kh = ri - r in [0,2]
#pragma unroll
            for (int r = 0; r < 4; ++r) {
                const int kh = ri - r;
                if (kh >= 0 && kh < 3) {
#pragma unroll
                    for (int kw = 0; kw < 3; ++kw) {
#pragma unroll
                        for (int oc = 0; oc < CH; ++oc) {
                            const float wv = wk[oc][kh][kw];
#pragma unroll
                            for (int j = 0; j < 8; ++j)
                                acc[oc][r][j] = fmaf(row[j + kw], wv, acc[oc][r][j]);
                        }
                    }
                }
            }
        }
    }

    float* ob = out + (size_t)b * CH * HW * HW + (size_t)hb * HW + w8;
#pragma unroll
    for (int oc = 0; oc < CH; ++oc) {
#pragma unroll
        for (int r = 0; r < 4; ++r) {
            float* dst = ob + (size_t)oc * HW * HW + (size_t)r * HW;
            v4f v0, v1;
            v0.x = acc[oc][r][0]; v0.y = acc[oc][r][1];
            v0.z = acc[oc][r][2]; v0.w = acc[oc][r][3];
            v1.x = acc[oc][r][4]; v1.y = acc[oc][r][5];
            v1.z = acc[oc][r][6]; v1.w = acc[oc][r][7];
            __builtin_nontemporal_store(v0, (v4f*)dst);
            __builtin_nontemporal_store(v1, (v4f*)(dst + 4));
        }
    }
}

extern "C" void kernel_launch(void* const* d_in, const int* in_sizes, int n_in,
                              void* d_out, int out_size, void* d_ws, size_t ws_size,
                              hipStream_t stream) {
    const float* img   = (const float*)d_in[0];  // [32,3,512,512]
    const float* Wt    = (const float*)d_in[1];  // [64,3,3,3,3]
    const float* bias  = (const float*)d_in[2];  // [64,3]
    const int*   alloc = (const int*)d_in[3];    // [32]
    float*       out   = (float*)d_out;          // [32,3,512,512]

    const int B = in_sizes[3];                   // 32
    dim3 grid(32, B);                            // 32 blocks x 256 thr = 8192 thr/sample
    dim3 block(256);
    moe_conv3x3_kernel<<<grid, block, 0, stream>>>(img, Wt, bias, alloc, out);
}

// Round 5
// 56.608 us; speedup vs baseline: 1.1835x; 1.1835x over previous
//
#include <hip/hip_runtime.h>
#include <hip/hip_bf16.h>

#define HW 512
#define CH 3

typedef float v4f __attribute__((ext_vector_type(4)));

// Wave-per-row-pair: each wave owns 2 full output rows (512 px, 3 oc).
// Lane l covers px [4l,4l+4) (group a) and [256+4l,256+4l+4) (group b).
// All horizontal halos via cross-lane __shfl; image edges via lane predicate.
// Every load/store instruction is lane-contiguous (16B stride) -> no
// partial-sector write amplification (R4 lesson).
__global__ __launch_bounds__(256) void moe_conv3x3_kernel(
    const float* __restrict__ img,   // [B,3,512,512]
    const float* __restrict__ Wt,    // [E,3,3,3,3] OIHW per expert
    const float* __restrict__ bias,  // [E,3]
    const int*   __restrict__ alloc, // [B]
    float*       __restrict__ out)   // [B,3,512,512]
{
    const int b = blockIdx.y;
    int e = alloc[b];
    e = __builtin_amdgcn_readfirstlane(e);   // wave-uniform -> s_loads

    const float* we = Wt + (size_t)e * (CH * CH * 9);
    float bv[CH];
#pragma unroll
    for (int oc = 0; oc < CH; ++oc) bv[oc] = bias[(size_t)e * CH + oc];

    const int tid  = threadIdx.x;
    const int lane = tid & 63;
    const int wid  = tid >> 6;
    const int rp   = blockIdx.x * 4 + wid;   // row-pair 0..255
    const int h0   = rp * 2;                 // output rows h0, h0+1

    const int  c0  = lane * 4;               // group-a col; group-b = c0+256
    const bool l0  = (lane == 0);
    const bool l63 = (lane == 63);

    const float* inb = img + (size_t)b * CH * HW * HW;

    float acc[CH][2][8];
#pragma unroll
    for (int oc = 0; oc < CH; ++oc)
#pragma unroll
        for (int r = 0; r < 2; ++r)
#pragma unroll
            for (int j = 0; j < 8; ++j) acc[oc][r][j] = bv[oc];

#pragma unroll
    for (int ci = 0; ci < CH; ++ci) {
        const float* inc = inb + (size_t)ci * HW * HW;

        float wk[CH][3][3];  // wave-uniform -> scalar regs
#pragma unroll
        for (int oc = 0; oc < CH; ++oc)
#pragma unroll
            for (int kh = 0; kh < 3; ++kh)
#pragma unroll
                for (int kw = 0; kw < 3; ++kw)
                    wk[oc][kh][kw] = we[((oc * CH + ci) * 3 + kh) * 3 + kw];

#pragma unroll
        for (int ri = 0; ri < 4; ++ri) {     // input rows h0-1 .. h0+2
            const int hr = h0 + ri - 1;
            v4f a, c;
            if (hr >= 0 && hr < HW) {        // wave-uniform branch
                const float* r = inc + (size_t)hr * HW;
                a = *(const v4f*)(r + c0);
                c = *(const v4f*)(r + 256 + c0);
            } else {
                a = (v4f)0.0f; c = (v4f)0.0f;
            }

            // horizontal halos via cross-lane shuffles
            float aL = __shfl(a.w, (lane + 63) & 63);        // px 4l-1
            aL = l0 ? 0.0f : aL;                             // image left edge
            float t1 = __shfl(a.x, (lane + 1) & 63);
            float t2 = __shfl(c.x, 0);                       // px 256
            float aR = l63 ? t2 : t1;                        // px 4l+4
            float t3 = __shfl(c.w, (lane + 63) & 63);
            float t4 = __shfl(a.w, 63);                      // px 255
            float bL = l0 ? t4 : t3;                         // px 255+4l
            float t5 = __shfl(c.x, (lane + 1) & 63);
            float bR = l63 ? 0.0f : t5;                      // px 260+4l / edge

            const float ax[6] = {aL, a.x, a.y, a.z, a.w, aR};
            const float bx[6] = {bL, c.x, c.y, c.z, c.w, bR};

            // input row ri -> output rows r with kh = ri - r in [0,2]
#pragma unroll
            for (int r = 0; r < 2; ++r) {
                const int kh = ri - r;
                if (kh >= 0 && kh < 3) {
#pragma unroll
                    for (int kw = 0; kw < 3; ++kw) {
#pragma unroll
                        for (int oc = 0; oc < CH; ++oc) {
                            const float wv = wk[oc][kh][kw];
#pragma unroll
                            for (int j = 0; j < 4; ++j) {
                                acc[oc][r][j]     = fmaf(ax[kw + j], wv, acc[oc][r][j]);
                                acc[oc][r][4 + j] = fmaf(bx[kw + j], wv, acc[oc][r][4 + j]);
                            }
                        }
                    }
                }
            }
        }
    }

    float* ob = out + (size_t)b * CH * HW * HW + (size_t)h0 * HW;
#pragma unroll
    for (int oc = 0; oc < CH; ++oc) {
#pragma unroll
        for (int r = 0; r < 2; ++r) {
            float* dst = ob + (size_t)oc * HW * HW + (size_t)r * HW;
            v4f v0, v1;
            v0.x = acc[oc][r][0]; v0.y = acc[oc][r][1];
            v0.z = acc[oc][r][2]; v0.w = acc[oc][r][3];
            v1.x = acc[oc][r][4]; v1.y = acc[oc][r][5];
            v1.z = acc[oc][r][6]; v1.w = acc[oc][r][7];
            __builtin_nontemporal_store(v0, (v4f*)(dst + c0));        // lane-contig
            __builtin_nontemporal_store(v1, (v4f*)(dst + 256 + c0));  // lane-contig
        }
    }
}

extern "C" void kernel_launch(void* const* d_in, const int* in_sizes, int n_in,
                              void* d_out, int out_size, void* d_ws, size_t ws_size,
                              hipStream_t stream) {
    const float* img   = (const float*)d_in[0];  // [32,3,512,512]
    const float* Wt    = (const float*)d_in[1];  // [64,3,3,3,3]
    const float* bias  = (const float*)d_in[2];  // [64,3]
    const int*   alloc = (const int*)d_in[3];    // [32]
    float*       out   = (float*)d_out;          // [32,3,512,512]

    const int B = in_sizes[3];                   // 32
    dim3 grid(64, B);   // 64 blocks x 4 waves = 256 row-pairs = 512 rows
    dim3 block(256);
    moe_conv3x3_kernel<<<grid, block, 0, stream>>>(img, Wt, bias, alloc, out);
}

// Round 6
// 42.000 us; speedup vs baseline: 1.5952x; 1.3478x over previous
//
#include <hip/hip_runtime.h>
#include <hip/hip_bf16.h>

#define HW 512
#define CH 3

typedef float v4f __attribute__((ext_vector_type(4)));

// R3 structure (best so far: 41 us). Single change vs R3: plain cached
// stores instead of nontemporal — steady-state graph replays keep the
// 96 MB output resident in L3 (192 MB working set < 256 MB L3), so dirty
// lines get overwritten before draining to HBM.
__global__ __launch_bounds__(256) void moe_conv3x3_kernel(
    const float* __restrict__ img,   // [B,3,512,512]
    const float* __restrict__ Wt,    // [E,3,3,3,3] OIHW per expert
    const float* __restrict__ bias,  // [E,3]
    const int*   __restrict__ alloc, // [B]
    float*       __restrict__ out)   // [B,3,512,512]
{
    const int b = blockIdx.y;
    int e = alloc[b];
    e = __builtin_amdgcn_readfirstlane(e);   // wave-uniform -> s_loads

    const float* we = Wt + (size_t)e * (CH * CH * 9);

    float bv[CH];
#pragma unroll
    for (int oc = 0; oc < CH; ++oc) bv[oc] = bias[(size_t)e * CH + oc];

    const int idx = blockIdx.x * 256 + threadIdx.x;  // 0..16383
    const int w4  = (idx & 127) * 4;                 // 0..508 step 4
    const int hb  = (idx >> 7) * 4;                  // 0..508 step 4

    const float* inb = img + (size_t)b * CH * HW * HW;

    float acc[CH][4][4];
#pragma unroll
    for (int oc = 0; oc < CH; ++oc)
#pragma unroll
        for (int r = 0; r < 4; ++r)
#pragma unroll
            for (int j = 0; j < 4; ++j) acc[oc][r][j] = bv[oc];

#pragma unroll
    for (int ci = 0; ci < CH; ++ci) {
        const float* inc = inb + (size_t)ci * HW * HW;

        float wk[CH][3][3];  // wave-uniform -> scalar regs
#pragma unroll
        for (int oc = 0; oc < CH; ++oc)
#pragma unroll
            for (int kh = 0; kh < 3; ++kh)
#pragma unroll
                for (int kw = 0; kw < 3; ++kw)
                    wk[oc][kh][kw] = we[((oc * CH + ci) * 3 + kh) * 3 + kw];

#pragma unroll
        for (int ri = 0; ri < 6; ++ri) {            // input rows hb-1 .. hb+4
            const int hr = hb + ri - 1;
            float row[6];
            if (hr >= 0 && hr < HW) {               // wave-uniform branch
                const float* rsrc = inc + (size_t)hr * HW + w4;
                const v4f v = *(const v4f*)rsrc;
                row[1] = v.x; row[2] = v.y; row[3] = v.z; row[4] = v.w;
                row[0] = (w4 > 0)      ? rsrc[-1] : 0.0f;
                row[5] = (w4 < HW - 4) ? rsrc[4]  : 0.0f;
            } else {
#pragma unroll
                for (int j = 0; j < 6; ++j) row[j] = 0.0f;
            }

#pragma unroll
            for (int r = 0; r < 4; ++r) {
                const int kh = ri - r;
                if (kh >= 0 && kh < 3) {
#pragma unroll
                    for (int kw = 0; kw < 3; ++kw) {
#pragma unroll
                        for (int oc = 0; oc < CH; ++oc) {
                            const float wv = wk[oc][kh][kw];
#pragma unroll
                            for (int j = 0; j < 4; ++j)
                                acc[oc][r][j] = fmaf(row[j + kw], wv, acc[oc][r][j]);
                        }
                    }
                }
            }
        }
    }

    float* ob = out + (size_t)b * CH * HW * HW + (size_t)hb * HW + w4;
#pragma unroll
    for (int oc = 0; oc < CH; ++oc) {
#pragma unroll
        for (int r = 0; r < 4; ++r) {
            v4f v;
            v.x = acc[oc][r][0]; v.y = acc[oc][r][1];
            v.z = acc[oc][r][2]; v.w = acc[oc][r][3];
            *(v4f*)(ob + (size_t)oc * HW * HW + (size_t)r * HW) = v;  // cached store
        }
    }
}

extern "C" void kernel_launch(void* const* d_in, const int* in_sizes, int n_in,
                              void* d_out, int out_size, void* d_ws, size_t ws_size,
                              hipStream_t stream) {
    const float* img   = (const float*)d_in[0];  // [32,3,512,512]
    const float* Wt    = (const float*)d_in[1];  // [64,3,3,3,3]
    const float* bias  = (const float*)d_in[2];  // [64,3]
    const int*   alloc = (const int*)d_in[3];    // [32]
    float*       out   = (float*)d_out;          // [32,3,512,512]

    const int B = in_sizes[3];                   // 32
    dim3 grid(64, B);                            // 64 blocks x 256 thr
    dim3 block(256);
    moe_conv3x3_kernel<<<grid, block, 0, stream>>>(img, Wt, bias, alloc, out);
}